// Round 2
// baseline (154.575 us; speedup 1.0000x reference)
//
#include <hip/hip_runtime.h>
#include <hip/hip_bf16.h>
#include <cstdint>
#include <cstddef>

#define NBATCH 8
#define NANCH 25500
#define MAXDET 300
#define NBINS 2048

typedef __bf16 bf16x8 __attribute__((ext_vector_type(8)));
typedef float floatx4 __attribute__((ext_vector_type(4)));
typedef unsigned long long ull;

__device__ __forceinline__ int conf_bin(float v) {
  unsigned bits = __float_as_uint(v);
  int bin = (int)((bits - 0x3D800000u) >> 14);   // [0.0625,1.0) -> 0..2047
  return bin > (NBINS - 1) ? (NBINS - 1) : bin;
}

// ---------------------------------------------------------------------------
// K1: conf = max_c(cls_c * obj), argmax class, threshold 0.1
// ---------------------------------------------------------------------------
#define CONF_TILE 64
__global__ __launch_bounds__(256) void conf_kernel(const float* __restrict__ preds,
                                                   float* __restrict__ conf,
                                                   int* __restrict__ cls, int total) {
  __shared__ float s[CONF_TILE * 85];
  int base = blockIdx.x * CONF_TILE;
  int nA = total - base; if (nA > CONF_TILE) nA = CONF_TILE;
  int n4 = (nA * 85) >> 2;
  const float4* g4 = (const float4*)(preds + (size_t)base * 85);
  float4* s4 = (float4*)s;
  for (int i = threadIdx.x; i < n4; i += 256) s4[i] = g4[i];
  __syncthreads();
  int lane16 = threadIdx.x & 15;
  int sub = threadIdx.x >> 4;
  #pragma unroll
  for (int r = 0; r < 4; ++r) {
    int a = r * 16 + sub;
    if (a < nA) {
      const float* row = s + a * 85;
      float obj = row[4];
      float best = -1.0f; int bc = 0;
      #pragma unroll
      for (int j = 0; j < 5; ++j) {
        int c = lane16 * 5 + j;
        float v = row[5 + c] * obj;    // exact IEEE mul, matches reference
        if (v > best) { best = v; bc = c; }
      }
      #pragma unroll
      for (int m = 1; m < 16; m <<= 1) {
        float ov = __shfl_xor(best, m, 64);
        int   oc = __shfl_xor(bc,   m, 64);
        if (ov > best || (ov == best && oc < bc)) { best = ov; bc = oc; }
      }
      if (lane16 == 0) {
        int idx = base + a;
        conf[idx] = (best > 0.1f) ? best : 0.0f;
        cls[idx] = bc;
      }
    }
  }
}

// ---------------------------------------------------------------------------
// K3: fused transposes + per-batch SELECT (blocks 0..7).
// Select role: 2048-bin LDS histogram of conf(batch), in-block suffix scan,
// threshold bin T for exact top-300, then re-scan conf and scatter each
// candidate (bin>=T) to global slot = suffix[bin+1] + arrival, gathering its
// box (from preds) and class. Also writes the suffix array + {total,Kslots}.
// Rank finalization (within-bin, ~12-25 members) happens in nms_kernel.
// Transpose role (blocks 8..): (C,HW)->(HW,C) fp32->bf16, 6 segments.
// ---------------------------------------------------------------------------
struct TransArgs {
  const float* src[6];
  __hip_bfloat16* dst[6];
  int C[6], HW[6], tx[6], tpb[6], start[6];
};

__global__ void transpose_all_kernel(TransArgs a,
                                     const float* __restrict__ conf,
                                     const float* __restrict__ preds,
                                     const int* __restrict__ clsg,
                                     float2* __restrict__ svid,
                                     float4* __restrict__ sbox,
                                     int* __restrict__ scls,
                                     int* __restrict__ sufG,
                                     int* __restrict__ tinfo) {
  __shared__ __align__(16) char msm[17536];
  int bid = blockIdx.x;
  if (bid < NBATCH) {
    // ---- select role ----
    #pragma clang fp contract(off)
    int b = bid;
    int tid = threadIdx.y * 32 + threadIdx.x;        // 0..255
    int* s_h   = (int*)msm;                          //  8192 B: hist -> suffix
    int* s_ctr = (int*)(msm + 8192);                 //  8192 B: scatter counters
    int* s_p   = (int*)(msm + 16384);                //  1024 B: chunk totals
    int* shv   = (int*)(msm + 17408);                //  [0] = T
    for (int i = tid; i < NBINS; i += 256) s_h[i] = 0;
    __syncthreads();
    const float* cf = conf + (size_t)b * NANCH;
    const float4* cf4 = (const float4*)cf;
    const int N4 = NANCH >> 2;                       // 6375 exactly
    for (int i = tid; i < N4; i += 256) {
      float4 v = cf4[i];
      if (v.x > 0.1f) atomicAdd(&s_h[conf_bin(v.x)], 1);
      if (v.y > 0.1f) atomicAdd(&s_h[conf_bin(v.y)], 1);
      if (v.z > 0.1f) atomicAdd(&s_h[conf_bin(v.z)], 1);
      if (v.w > 0.1f) atomicAdd(&s_h[conf_bin(v.w)], 1);
    }
    __syncthreads();
    // suffix scan: 8 bins per thread, then Hillis suffix over 256 chunk sums
    int base = tid * 8;
    int vals[8]; int ctot = 0;
    #pragma unroll
    for (int k = 0; k < 8; ++k) { vals[k] = s_h[base + k]; ctot += vals[k]; }
    s_p[tid] = ctot;
    __syncthreads();
    for (int off = 1; off < 256; off <<= 1) {
      int v = (tid + off < 256) ? s_p[tid + off] : 0;
      __syncthreads();
      s_p[tid] += v;
      __syncthreads();
    }
    int total = s_p[0];
    int above = (tid < 255) ? s_p[tid + 1] : 0;
    int run = above;
    #pragma unroll
    for (int k = 7; k >= 0; --k) { run += vals[k]; s_h[base + k] = run; } // s_h[bin]=suffix
    if (tid == 0) { sufG[b * (NBINS + 1) + NBINS] = 0; shv[0] = NBINS; }
    __syncthreads();
    int target = total < 300 ? total : 300;
    int* sg = sufG + b * (NBINS + 1);
    #pragma unroll
    for (int k = 0; k < 8; ++k) {
      int bin = base + k;
      int sv = s_h[bin];
      int nx = (bin < NBINS - 1) ? s_h[bin + 1] : 0;
      s_ctr[bin] = nx;                               // scatter base = suffix[bin+1]
      sg[bin] = sv;
      if (total > 0 && sv >= target && nx < target) shv[0] = bin;  // unique boundary
    }
    __syncthreads();
    int T = shv[0];
    if (tid == 0) {
      tinfo[b * 2 + 0] = total;
      tinfo[b * 2 + 1] = (T < NBINS) ? s_h[T] : 0;   // Kslots
    }
    if (total > 0) {
      float2* vb = svid + (size_t)b * NANCH;
      float4* bb = sbox + (size_t)b * NANCH;
      int*    cb = scls + (size_t)b * NANCH;
      for (int i4 = tid; i4 < N4; i4 += 256) {
        float4 v4 = cf4[i4];
        int i0 = i4 * 4;
        float vv[4] = {v4.x, v4.y, v4.z, v4.w};
        #pragma unroll
        for (int q = 0; q < 4; ++q) {
          float v = vv[q];
          if (v > 0.1f) {
            int bin = conf_bin(v);
            if (bin >= T) {
              int slot = atomicAdd(&s_ctr[bin], 1);
              int idx = i0 + q;
              const float* p = preds + ((size_t)b * NANCH + idx) * 85;
              float cx = p[0], cy = p[1], w = p[2], h = p[3];
              float hw2 = w * 0.5f, hh2 = h * 0.5f;
              float2 vi; vi.x = v; vi.y = __int_as_float(idx);
              vb[slot] = vi;
              float4 bx; bx.x = cx - hw2; bx.y = cy - hh2; bx.z = cx + hw2; bx.w = cy + hh2;
              bb[slot] = bx;
              cb[slot] = clsg[(size_t)b * NANCH + idx];
            }
          }
        }
      }
    }
    return;
  }
  // ---- transpose role ----
  float (*tile)[33] = (float(*)[33])msm;
  int s = 0;
  #pragma unroll
  for (int i = 1; i < 6; ++i) if (bid >= a.start[i]) s = i;
  int local = bid - a.start[s];
  int C = a.C[s], HW = a.HW[s], tx0 = a.tx[s], tpb = a.tpb[s];
  int b = local / tpb;
  int rem = local - b * tpb;
  int p0 = (rem % tx0) * 32;
  int c0 = (rem / tx0) * 32;
  const float* inb = a.src[s] + (size_t)b * C * HW;
  __hip_bfloat16* outb = a.dst[s] + (size_t)b * C * HW;
  int tx = threadIdx.x, ty = threadIdx.y;   // 32 x 8
  #pragma unroll
  for (int k = 0; k < 32; k += 8) {
    int c = c0 + ty + k, p = p0 + tx;
    if (c < C && p < HW) tile[ty + k][tx] = inb[(size_t)c * HW + p];
  }
  __syncthreads();
  #pragma unroll
  for (int k = 0; k < 32; k += 8) {
    int p = p0 + ty + k, c = c0 + tx;
    if (p < HW && c < C) outb[(size_t)p * C + c] = __float2bfloat16(tile[tx][ty + k]);
  }
}

// ---------------------------------------------------------------------------
// K2: per-batch rank finalize + NMS. One block (1024 threads) per batch.
// Rank = suffix[bin+1] + within-bin rank (segment reads from global, ~12-25
// per candidate, per-lane parallel). Scatter offset-boxes (float4) + raw
// boxes into LDS by rank, build IOU ballot mask with ds_read_b128 row
// broadcasts, ctz skip-chain suppression, rescale, write output cols 0..3.
// fp contract OFF for bitwise-matching IOU.
// ---------------------------------------------------------------------------
__global__ __launch_bounds__(1024) void nms_kernel(const float2* __restrict__ svid,
                                                   const float4* __restrict__ sbox,
                                                   const int* __restrict__ scls,
                                                   const int* __restrict__ sufG,
                                                   const int* __restrict__ tinfo,
                                                   float* __restrict__ boxesWs, int* __restrict__ keepWs,
                                                   const float* __restrict__ orig_hw,
                                                   float* __restrict__ out) {
  #pragma clang fp contract(off)
  __shared__ float4 bo4[300];       // offset boxes (area recomputed bit-exact)
  __shared__ float bxx[300][4];     // raw boxes for rescale
  __shared__ ull mask[300][5];
  __shared__ ull keepw[5];
  __shared__ ull nzrow[5];
  int b = blockIdx.x;
  int t = threadIdx.x;
  int total  = tinfo[b * 2 + 0];
  int Kslots = tinfo[b * 2 + 1];
  int nvalid = total < 300 ? total : 300;

  // init: zero boxes (covers total<300 ranks), keep bits = [0,nvalid)
  if (t < 300) {
    bo4[t] = make_float4(0.0f, 0.0f, 0.0f, 0.0f);
    bxx[t][0] = 0.0f; bxx[t][1] = 0.0f; bxx[t][2] = 0.0f; bxx[t][3] = 0.0f;
    if (t >= nvalid) {
      size_t bi = ((size_t)(b * 300 + t)) * 4;
      boxesWs[bi + 0] = 0.0f; boxesWs[bi + 1] = 0.0f;
      boxesWs[bi + 2] = 0.0f; boxesWs[bi + 3] = 0.0f;
    }
  }
  if (t < 5) {
    int kbase = t * 64;
    int n = nvalid - kbase;
    keepw[t] = (n <= 0) ? 0ULL : (n >= 64 ? ~0ULL : ((1ULL << n) - 1ULL));
    nzrow[t] = 0ULL;
  }
  __syncthreads();

  // rank finalize + scatter
  {
    const float2* vb = svid + (size_t)b * NANCH;
    const float4* bb = sbox + (size_t)b * NANCH;
    const int*    cb = scls + (size_t)b * NANCH;
    const int*   suf = sufG + b * (NBINS + 1);
    for (int sIdx = t; sIdx < Kslots; sIdx += 1024) {
      float2 vi = vb[sIdx];
      float v = vi.x;
      int id = __float_as_int(vi.y);
      int bin = conf_bin(v);
      int lo = suf[bin + 1], hi = suf[bin];
      int rank = lo;
      for (int j = lo; j < hi; ++j) {
        float2 o = vb[j];
        float vj = o.x;
        int ij = __float_as_int(o.y);
        rank += (int)((vj > v) | ((vj == v) & (ij < id)));
      }
      if (rank < 300) {
        float4 bx = bb[sIdx];
        int c = cb[sIdx];
        float off = (float)c * 4096.0f;
        float4 ob; ob.x = bx.x + off; ob.y = bx.y + off; ob.z = bx.z + off; ob.w = bx.w + off;
        bo4[rank] = ob;
        bxx[rank][0] = bx.x; bxx[rank][1] = bx.y; bxx[rank][2] = bx.z; bxx[rank][3] = bx.w;
        size_t bi = ((size_t)(b * 300 + rank)) * 4;
        boxesWs[bi + 0] = bx.x; boxesWs[bi + 1] = bx.y;
        boxesWs[bi + 2] = bx.z; boxesWs[bi + 3] = bx.w;
      }
    }
  }
  __syncthreads();

  // IOU ballot mask: 10 waves; one ds_read_b128 broadcast per row
  {
    int wv = t >> 6, ln = t & 63;
    if (wv < 10) {
      int w = wv >> 1, half = wv & 1;
      int j = w * 64 + ln;
      int jc = j < 300 ? j : 0;
      float4 jb = bo4[jc];
      float ja = (jb.z - jb.x) * (jb.w - jb.y);
      bool jv = j < 300;
      int iend = w * 64 + 64; if (iend > 300) iend = 300;
      int i0 = half * 150, i1 = i0 + 150; if (i1 > iend) i1 = iend;
      #pragma unroll 4
      for (int i = i0; i < i1; ++i) {
        float4 ib = bo4[i];
        float ai = (ib.z - ib.x) * (ib.w - ib.y);
        float ltx = fmaxf(ib.x, jb.x);
        float lty = fmaxf(ib.y, jb.y);
        float rbx = fminf(ib.z, jb.z);
        float rby = fminf(ib.w, jb.w);
        float wx = fmaxf(rbx - ltx, 0.0f);
        float wy = fmaxf(rby - lty, 0.0f);
        float inter = wx * wy;
        float iou = inter / (ai + ja - inter + 1e-7f);
        ull bal = __ballot(jv && (j > i) && (iou > 0.6f));
        if (ln == 0) {
          mask[i][w] = bal;
          if (bal) atomicOr(&nzrow[i >> 6], 1ULL << (i & 63));
        }
      }
    }
  }
  __syncthreads();
  if (t == 0) {
    ull kw[5], nz[5];
    #pragma unroll
    for (int w = 0; w < 5; ++w) { kw[w] = keepw[w]; nz[w] = nzrow[w]; }
    #pragma unroll
    for (int w = 0; w < 5; ++w) {
      ull p = kw[w] & nz[w];
      while (p) {
        int l = __builtin_ctzll(p);
        p &= p - 1;
        int i = w * 64 + l;
        for (int w2 = w; w2 < 5; ++w2) {
          ull m = mask[i][w2];
          kw[w2] &= ~m;
          if (w2 == w) p &= ~m;
        }
      }
    }
    #pragma unroll
    for (int w = 0; w < 5; ++w) keepw[w] = kw[w];
  }
  __syncthreads();
  if (t < 300) {
    int kp = (int)((keepw[t >> 6] >> (t & 63)) & 1ULL);
    keepWs[b * 300 + t] = kp;
    float oh = orig_hw[b * 2 + 0], ow = orig_hw[b * 2 + 1];
    float gain = fminf(640.0f / oh, 640.0f / ow);
    float padx = (640.0f - ow * gain) * 0.5f;
    float pady = (640.0f - oh * gain) * 0.5f;
    float x1 = fminf(fmaxf((bxx[t][0] - padx) / gain, 0.0f), ow) / ow;
    float y1 = fminf(fmaxf((bxx[t][1] - pady) / gain, 0.0f), oh) / oh;
    float x2 = fminf(fmaxf((bxx[t][2] - padx) / gain, 0.0f), ow) / ow;
    float y2 = fminf(fmaxf((bxx[t][3] - pady) / gain, 0.0f), oh) / oh;
    size_t o = ((size_t)(b * 300 + t)) * 260;
    out[o + 0] = kp ? x1 : 0.0f;
    out[o + 1] = kp ? y1 : 0.0f;
    out[o + 2] = kp ? x2 : 0.0f;
    out[o + 3] = kp ? y2 : 0.0f;
  }
}

// ---------------------------------------------------------------------------
// K4: ROI-align 1x1 over 4 levels from HWC bf16 features -> bf16 fmat rows.
// XCD-affinity: b = blockIdx.x & 7 so every block of batch b lands on XCD b.
// ---------------------------------------------------------------------------
__global__ __launch_bounds__(256) void roi_kernel(const float* __restrict__ boxes,
                                                  const __hip_bfloat16* __restrict__ fT1, const __hip_bfloat16* __restrict__ fT2,
                                                  const __hip_bfloat16* __restrict__ fT3, const __hip_bfloat16* __restrict__ fT4,
                                                  __hip_bfloat16* __restrict__ f) {
  int b = blockIdx.x & 7;
  int r = blockIdx.x >> 3;
  __shared__ int t_off[4][16];
  __shared__ float t_w[4][16];
  int t = threadIdx.x;
  const int Hs[4] = {80, 40, 20, 10};
  const int Cs[4] = {128, 256, 512, 1024};
  const float ss[4] = {0.125f, 0.0625f, 0.03125f, 0.015625f};
  size_t bbase = ((size_t)(b * 300 + r)) * 4;
  float bx0 = boxes[bbase + 0];
  float by0 = boxes[bbase + 1];
  float bx1 = boxes[bbase + 2];
  float by1 = boxes[bbase + 3];
  if (t < 64) {
    int lv = t >> 4, k = t & 15, pp = k >> 2, nb = k & 3;
    float s = ss[lv];
    int H = Hs[lv], W = Hs[lv], C = Cs[lv];
    float b0 = bx0 * s, b1 = by0 * s, b2 = bx1 * s, b3 = by1 * s;
    float w = fmaxf(b2 - b0, 1.0f), h = fmaxf(b3 - b1, 1.0f);
    const float offv[2] = {0.5f, 1.5f};
    float px = b0 + offv[pp & 1] * (w * 0.5f);
    float py = b1 + offv[pp >> 1] * (h * 0.5f);
    float y = fminf(fmaxf(py, 0.0f), (float)(H - 1));
    float x = fminf(fmaxf(px, 0.0f), (float)(W - 1));
    int y0 = (int)floorf(y), x0 = (int)floorf(x);
    int y1 = min(y0 + 1, H - 1), x1 = min(x0 + 1, W - 1);
    float ly = y - (float)y0, lx = x - (float)x0;
    int yy = (nb & 2) ? y1 : y0;
    int xx = (nb & 1) ? x1 : x0;
    float wy = (nb & 2) ? ly : (1.0f - ly);
    float wx = (nb & 1) ? lx : (1.0f - lx);
    t_off[lv][k] = (yy * W + xx) * C;
    t_w[lv][k] = wy * wx;
  }
  __syncthreads();
  const __hip_bfloat16* bases[4] = {
    fT1 + (size_t)b * 6400 * 128,
    fT2 + (size_t)b * 1600 * 256,
    fT3 + (size_t)b * 400 * 512,
    fT4 + (size_t)b * 100 * 1024
  };
  __hip_bfloat16* frow = f + (size_t)(b * 300 + r) * 1920;
  int cbase = 0;
  #pragma unroll
  for (int lv = 0; lv < 4; ++lv) {
    int C = Cs[lv];
    const __hip_bfloat16* base = bases[lv];
    for (int c = t; c < C; c += 256) {
      float acc = 0.0f;
      #pragma unroll
      for (int k = 0; k < 16; ++k)
        acc += t_w[lv][k] * __bfloat162float(base[t_off[lv][k] + c]);
      frow[cbase + c] = __float2bfloat16(acc * 0.25f);
    }
    cbase += C;
  }
}

// ---------------------------------------------------------------------------
// K5/K6: staged bf16 MFMA GEMM. BM=BN=BK=64, 4 waves/block (each 32x32),
// double-buffered LDS via global_load_lds(16B) with both-sides XOR swizzle.
// ---------------------------------------------------------------------------
#define GLDS16(gp, lp) __builtin_amdgcn_global_load_lds( \
    (const __attribute__((address_space(1))) unsigned int*)(gp), \
    (__attribute__((address_space(3))) unsigned int*)(lp), 16, 0, 0)

__global__ __launch_bounds__(256) void gemm_tile_kernel(const __hip_bfloat16* __restrict__ A,
                                                        const __hip_bfloat16* __restrict__ BT,
                                                        const float* __restrict__ bias,
                                                        __hip_bfloat16* __restrict__ Cb,
                                                        float* __restrict__ Cf,
                                                        const int* __restrict__ keep,
                                                        int M, int N, int K, int ldc, int coff) {
  __shared__ __hip_bfloat16 sA[2][64 * 64];
  __shared__ __hip_bfloat16 sB[2][64 * 64];
  int tid = threadIdx.x;
  int bm = blockIdx.x * 64, bn = blockIdx.y * 64;
  int wave = tid >> 6, lane = tid & 63;
  int wr = wave >> 1, wc = wave & 1;
  int idx16 = lane & 15, kb = lane >> 4;
  floatx4 acc[2][2] = {};
  int nt = K >> 6;

  auto stage = [&](int buf, int t) {
    int k0 = t << 6;
    #pragma unroll
    for (int i = 0; i < 2; ++i) {
      int c = tid + i * 256;
      int row = c >> 3, cc = c & 7;
      int scc = cc ^ (row & 7);
      GLDS16(A + (size_t)(bm + row) * K + k0 + scc * 8,
             (char*)&sA[buf][0] + c * 16);
    }
    #pragma unroll
    for (int i = 0; i < 2; ++i) {
      int c = tid + i * 256;
      int row = c >> 3, cc = c & 7;
      int scc = cc ^ (row & 7);
      GLDS16(BT + (size_t)(bn + row) * K + k0 + scc * 8,
             (char*)&sB[buf][0] + c * 16);
    }
  };

  stage(0, 0);
  asm volatile("s_waitcnt vmcnt(0)" ::: "memory");
  __syncthreads();
  int cur = 0;
  for (int t = 0; t < nt; ++t) {
    if (t + 1 < nt) stage(cur ^ 1, t + 1);
    const char* Ab = (const char*)&sA[cur][0];
    const char* Bb = (const char*)&sB[cur][0];
    #pragma unroll
    for (int s = 0; s < 2; ++s) {
      bf16x8 af[2], bg[2];
      #pragma unroll
      for (int m = 0; m < 2; ++m) {
        int row = wr * 32 + m * 16 + idx16;
        int chunk = s * 4 + kb;
        af[m] = *(const bf16x8*)(Ab + row * 128 + ((chunk ^ (row & 7)) * 16));
      }
      #pragma unroll
      for (int n = 0; n < 2; ++n) {
        int row = wc * 32 + n * 16 + idx16;
        int chunk = s * 4 + kb;
        bg[n] = *(const bf16x8*)(Bb + row * 128 + ((chunk ^ (row & 7)) * 16));
      }
      #pragma unroll
      for (int m = 0; m < 2; ++m)
        #pragma unroll
        for (int n = 0; n < 2; ++n)
          acc[m][n] = __builtin_amdgcn_mfma_f32_16x16x32_bf16(af[m], bg[n], acc[m][n], 0, 0, 0);
    }
    asm volatile("s_waitcnt vmcnt(0)" ::: "memory");
    __syncthreads();
    cur ^= 1;
  }
  int col = lane & 15, rb4 = (lane >> 4) * 4;
  #pragma unroll
  for (int m = 0; m < 2; ++m) {
    #pragma unroll
    for (int n = 0; n < 2; ++n) {
      #pragma unroll
      for (int r = 0; r < 4; ++r) {
        int orow = bm + wr * 32 + m * 16 + rb4 + r;
        int ocol = bn + wc * 32 + n * 16 + col;
        if (orow >= M) continue;
        float v = acc[m][n][r] + bias[ocol];
        v = (v >= 0.0f) ? v : 0.01f * v;
        if (Cb) Cb[(size_t)orow * N + ocol] = __float2bfloat16(v);
        if (Cf) {
          float km = keep ? (keep[orow] ? 1.0f : 0.0f) : 1.0f;
          Cf[(size_t)orow * ldc + coff + ocol] = v * km;
        }
      }
    }
  }
}

// ---------------------------------------------------------------------------
extern "C" void kernel_launch(void* const* d_in, const int* in_sizes, int n_in,
                              void* d_out, int out_size, void* d_ws, size_t ws_size,
                              hipStream_t stream) {
  (void)in_sizes; (void)n_in; (void)out_size; (void)ws_size;
  const float* preds  = (const float*)d_in[0];
  const float* feat1  = (const float*)d_in[1];
  const float* feat2  = (const float*)d_in[2];
  const float* feat3  = (const float*)d_in[3];
  const float* feat4  = (const float*)d_in[4];
  const float* orighw = (const float*)d_in[5];
  const float* W1     = (const float*)d_in[6];
  const float* b1     = (const float*)d_in[7];
  const float* W2     = (const float*)d_in[8];
  const float* b2     = (const float*)d_in[9];
  float* out = (float*)d_out;

  char* ws = (char*)d_ws;
  size_t off = 0;
  auto alloc = [&](size_t bytes) -> void* {
    void* p = ws + off;
    off = (off + bytes + 255) & ~(size_t)255;
    return p;
  };
  const int BN = NBATCH * NANCH;   // 204000
  float*  conf  = (float*)alloc((size_t)BN * 4);
  int*    cls   = (int*)  alloc((size_t)BN * 4);
  float2* svid  = (float2*)alloc((size_t)BN * 8);
  float4* sbox  = (float4*)alloc((size_t)BN * 16);
  int*    scls  = (int*)  alloc((size_t)BN * 4);
  int*    sufG  = (int*)  alloc((size_t)NBATCH * (NBINS + 1) * 4);
  int*    tinfo = (int*)  alloc((size_t)NBATCH * 2 * 4);
  float*  boxes = (float*)alloc((size_t)NBATCH * 300 * 4 * 4);
  int*    keep  = (int*)  alloc((size_t)NBATCH * 300 * 4);
  __hip_bfloat16* fT1  = (__hip_bfloat16*)alloc((size_t)NBATCH * 6400 * 128 * 2);
  __hip_bfloat16* fT2  = (__hip_bfloat16*)alloc((size_t)NBATCH * 1600 * 256 * 2);
  __hip_bfloat16* fT3  = (__hip_bfloat16*)alloc((size_t)NBATCH * 400 * 512 * 2);
  __hip_bfloat16* fT4  = (__hip_bfloat16*)alloc((size_t)NBATCH * 100 * 1024 * 2);
  __hip_bfloat16* fmat = (__hip_bfloat16*)alloc((size_t)2400 * 1920 * 2);
  __hip_bfloat16* h1b  = (__hip_bfloat16*)alloc((size_t)2400 * 256 * 2);
  __hip_bfloat16* W1T  = (__hip_bfloat16*)alloc((size_t)256 * 1920 * 2);
  __hip_bfloat16* W2T  = (__hip_bfloat16*)alloc((size_t)256 * 256 * 2);

  conf_kernel<<<(BN + CONF_TILE - 1) / CONF_TILE, 256, 0, stream>>>(preds, conf, cls, BN);

  // fused transposes (blocks 8..) + 8 select blocks (0..7)
  TransArgs ta;
  ta.src[0] = feat1; ta.dst[0] = fT1; ta.C[0] = 128;  ta.HW[0] = 6400; ta.tx[0] = 200;
  ta.src[1] = feat2; ta.dst[1] = fT2; ta.C[1] = 256;  ta.HW[1] = 1600; ta.tx[1] = 50;
  ta.src[2] = feat3; ta.dst[2] = fT3; ta.C[2] = 512;  ta.HW[2] = 400;  ta.tx[2] = 13;
  ta.src[3] = feat4; ta.dst[3] = fT4; ta.C[3] = 1024; ta.HW[3] = 100;  ta.tx[3] = 4;
  ta.src[4] = W1;    ta.dst[4] = W1T; ta.C[4] = 1920; ta.HW[4] = 256;  ta.tx[4] = 8;
  ta.src[5] = W2;    ta.dst[5] = W2T; ta.C[5] = 256;  ta.HW[5] = 256;  ta.tx[5] = 8;
  int total_blocks = NBATCH;   // select blocks first
  for (int s = 0; s < 6; ++s) {
    int ty = (ta.C[s] + 31) / 32;
    int nbatch = (s < 4) ? NBATCH : 1;
    ta.tpb[s] = ta.tx[s] * ty;
    ta.start[s] = total_blocks;
    total_blocks += ta.tpb[s] * nbatch;
  }
  transpose_all_kernel<<<total_blocks, dim3(32, 8), 0, stream>>>(ta, conf, preds, cls,
                                                                 svid, sbox, scls, sufG, tinfo);

  nms_kernel<<<NBATCH, 1024, 0, stream>>>(svid, sbox, scls, sufG, tinfo,
                                          boxes, keep, orighw, out);
  roi_kernel<<<2400, 256, 0, stream>>>(boxes, fT1, fT2, fT3, fT4, fmat);
  gemm_tile_kernel<<<dim3(38, 4), 256, 0, stream>>>(fmat, W1T, b1, h1b, nullptr, nullptr,
                                                    2400, 256, 1920, 0, 0);
  gemm_tile_kernel<<<dim3(38, 4), 256, 0, stream>>>(h1b, W2T, b2, nullptr, out, keep,
                                                    2400, 256, 256, 260, 4);
}

// Round 3
// 133.283 us; speedup vs baseline: 1.1598x; 1.1598x over previous
//
#include <hip/hip_runtime.h>
#include <hip/hip_bf16.h>
#include <cstdint>
#include <cstddef>

#define NBATCH 8
#define NANCH 25500
#define MAXDET 300
#define NBINS 2048
#define CAP 2048

typedef __bf16 bf16x8 __attribute__((ext_vector_type(8)));
typedef float floatx4 __attribute__((ext_vector_type(4)));
typedef unsigned long long ull;

__device__ __forceinline__ int conf_bin(float v) {
  unsigned bits = __float_as_uint(v);
  int bin = (int)((bits - 0x3D800000u) >> 14);   // [0.0625,1.0) -> 0..2047
  return bin > (NBINS - 1) ? (NBINS - 1) : bin;
}

// ---------------------------------------------------------------------------
// K1: conf = max_c(cls_c * obj), argmax class, threshold 0.1.
// Blocks 0..15 also zero ghist (8 x 2048 ints) for the next kernel.
// ---------------------------------------------------------------------------
#define CONF_TILE 64
__global__ __launch_bounds__(256) void conf_kernel(const float* __restrict__ preds,
                                                   float* __restrict__ conf,
                                                   int* __restrict__ cls,
                                                   int* __restrict__ ghist, int total) {
  if (blockIdx.x < 16) {
    #pragma unroll
    for (int k = 0; k < 4; ++k)
      ghist[blockIdx.x * 1024 + k * 256 + threadIdx.x] = 0;
  }
  __shared__ float s[CONF_TILE * 85];
  int base = blockIdx.x * CONF_TILE;
  int nA = total - base; if (nA > CONF_TILE) nA = CONF_TILE;
  int n4 = (nA * 85) >> 2;
  const float4* g4 = (const float4*)(preds + (size_t)base * 85);
  float4* s4 = (float4*)s;
  for (int i = threadIdx.x; i < n4; i += 256) s4[i] = g4[i];
  __syncthreads();
  int lane16 = threadIdx.x & 15;
  int sub = threadIdx.x >> 4;
  #pragma unroll
  for (int r = 0; r < 4; ++r) {
    int a = r * 16 + sub;
    if (a < nA) {
      const float* row = s + a * 85;
      float obj = row[4];
      float best = -1.0f; int bc = 0;
      #pragma unroll
      for (int j = 0; j < 5; ++j) {
        int c = lane16 * 5 + j;
        float v = row[5 + c] * obj;    // exact IEEE mul, matches reference
        if (v > best) { best = v; bc = c; }
      }
      #pragma unroll
      for (int m = 1; m < 16; m <<= 1) {
        float ov = __shfl_xor(best, m, 64);
        int   oc = __shfl_xor(bc,   m, 64);
        if (ov > best || (ov == best && oc < bc)) { best = ov; bc = oc; }
      }
      if (lane16 == 0) {
        int idx = base + a;
        conf[idx] = (best > 0.1f) ? best : 0.0f;
        cls[idx] = bc;
      }
    }
  }
}

// ---------------------------------------------------------------------------
// K3: 64 histogram blocks (first, so they overlap the transposes) + fused
// (C,HW)->(HW,C) fp32->bf16 transposes (6 segments).
// Hist role: per (batch, 1/8-segment) 2048-bin LDS histogram of conf,
// flushed to ghist via global atomics on nonzero bins only (~300/block).
// ---------------------------------------------------------------------------
struct TransArgs {
  const float* src[6];
  __hip_bfloat16* dst[6];
  int C[6], HW[6], tx[6], tpb[6], start[6];
};

__global__ void transpose_all_kernel(TransArgs a, const float* __restrict__ conf,
                                     int* __restrict__ ghist) {
  __shared__ __align__(16) char msm[8192];
  int bid = blockIdx.x;
  if (bid < 64) {
    // ---- histogram role ----
    int* sh = (int*)msm;                       // 2048 bins
    int b = bid >> 3, seg = bid & 7;
    int tid = threadIdx.y * 32 + threadIdx.x;  // 0..255
    for (int i = tid; i < NBINS; i += 256) sh[i] = 0;
    __syncthreads();
    const int N4 = NANCH >> 2;                 // 6375
    int i0 = (N4 * seg) >> 3, i1 = (N4 * (seg + 1)) >> 3;
    const float4* cf4 = (const float4*)(conf + (size_t)b * NANCH);
    for (int i = i0 + tid; i < i1; i += 256) {
      float4 v = cf4[i];
      if (v.x > 0.1f) atomicAdd(&sh[conf_bin(v.x)], 1);
      if (v.y > 0.1f) atomicAdd(&sh[conf_bin(v.y)], 1);
      if (v.z > 0.1f) atomicAdd(&sh[conf_bin(v.z)], 1);
      if (v.w > 0.1f) atomicAdd(&sh[conf_bin(v.w)], 1);
    }
    __syncthreads();
    for (int i = tid; i < NBINS; i += 256) {
      int c = sh[i];
      if (c) atomicAdd(&ghist[b * NBINS + i], c);
    }
    return;
  }
  // ---- transpose role ----
  int bid2 = bid - 64;
  float (*tile)[33] = (float(*)[33])msm;
  int s = 0;
  #pragma unroll
  for (int i = 1; i < 6; ++i) if (bid2 >= a.start[i]) s = i;
  int local = bid2 - a.start[s];
  int C = a.C[s], HW = a.HW[s], tx0 = a.tx[s], tpb = a.tpb[s];
  int b = local / tpb;
  int rem = local - b * tpb;
  int p0 = (rem % tx0) * 32;
  int c0 = (rem / tx0) * 32;
  const float* inb = a.src[s] + (size_t)b * C * HW;
  __hip_bfloat16* outb = a.dst[s] + (size_t)b * C * HW;
  int tx = threadIdx.x, ty = threadIdx.y;   // 32 x 8
  #pragma unroll
  for (int k = 0; k < 32; k += 8) {
    int c = c0 + ty + k, p = p0 + tx;
    if (c < C && p < HW) tile[ty + k][tx] = inb[(size_t)c * HW + p];
  }
  __syncthreads();
  #pragma unroll
  for (int k = 0; k < 32; k += 8) {
    int p = p0 + ty + k, c = c0 + tx;
    if (p < HW && c < C) outb[(size_t)p * C + c] = __float2bfloat16(tile[tx][ty + k]);
  }
}

// ---------------------------------------------------------------------------
// K2: per-batch select + rank + NMS. One block (1024 threads) per batch.
// Load prebuilt 2048-bin hist, Hillis suffix-scan, find threshold bin T for
// exact top-300, scan conf once scattering candidates (bin>=T, ~320) into
// LDS bin-segments, exact rank = segment base + within-bin rank (~20 LDS
// reads each, per-lane parallel), gather survivor boxes from preds, then
// float4-IOU ballot NMS + ctz skip-chain suppression + rescale + out cols
// 0..3. fp contract OFF for bitwise-matching IOU/boxes.
// ---------------------------------------------------------------------------
__global__ __launch_bounds__(1024) void nms_kernel(const float* __restrict__ conf,
                                                   const float* __restrict__ preds,
                                                   const int* __restrict__ clsg,
                                                   const int* __restrict__ ghist,
                                                   float* __restrict__ cand_v, int* __restrict__ cand_i,
                                                   float* __restrict__ boxesWs, int* __restrict__ keepWs,
                                                   const float* __restrict__ orig_hw,
                                                   float* __restrict__ out) {
  #pragma clang fp contract(off)
  __shared__ __align__(16) char smem[46592];
  // layout:
  //  s_h   @0      (8192)  suffix array, live until rank done
  //  s_p   @8192   (4096)  scan partials (dead after scan)
  //  s_ctr @12288  (8192)  scatter counters (dead after scatter)
  //  mask  @8192   (12000) overlay of s_p+s_ctr, live in IOU phase
  //  lv_s  @20480  (8192)  candidate values (dead after rank)
  //  li_s  @28672  (8192)  candidate indices (dead after rank)
  //  bo4   @36864  (4800)  offset boxes float4
  //  bxx   @41664  (4800)  raw boxes
  //  keepw @46464, nzrow @46504, shv @46544
  int*    s_h  = (int*)smem;
  int*    s_p  = (int*)(smem + 8192);
  int*    s_ctr= (int*)(smem + 12288);
  ull   (*mask)[5] = (ull(*)[5])(smem + 8192);
  float*  lv_s = (float*)(smem + 20480);
  int*    li_s = (int*)(smem + 28672);
  float4* bo4  = (float4*)(smem + 36864);
  float (*bxx)[4] = (float(*)[4])(smem + 41664);
  ull* keepw = (ull*)(smem + 46464);
  ull* nzrow = (ull*)(smem + 46504);
  int* shv   = (int*)(smem + 46544);
  int b = blockIdx.x;
  int t = threadIdx.x;

  // load hist; zero bo4/bxx; init flags
  for (int i = t; i < NBINS; i += 1024) s_h[i] = ghist[b * NBINS + i];
  if (t < 300) {
    bo4[t] = make_float4(0.0f, 0.0f, 0.0f, 0.0f);
    bxx[t][0] = 0.0f; bxx[t][1] = 0.0f; bxx[t][2] = 0.0f; bxx[t][3] = 0.0f;
  }
  if (t == 0) shv[0] = NBINS;
  if (t < 5) nzrow[t] = 0ULL;
  __syncthreads();

  // suffix scan over 2048 bins: 2 bins/thread + Hillis suffix over 1024
  int base = t * 2;
  int v0 = s_h[base], v1 = s_h[base + 1];
  s_p[t] = v0 + v1;
  __syncthreads();
  for (int off = 1; off < 1024; off <<= 1) {
    int v = (t + off < 1024) ? s_p[t + off] : 0;
    __syncthreads();
    s_p[t] += v;
    __syncthreads();
  }
  int total = s_p[0];
  int above = (t < 1023) ? s_p[t + 1] : 0;
  s_h[base + 1] = v1 + above;            // suffix[base+1]
  s_h[base]     = v0 + v1 + above;       // suffix[base]
  __syncthreads();

  int nvalid = total < 300 ? total : 300;
  int target = nvalid;
  if (total > 0) {
    int sv = s_h[base], nx = s_h[base + 1];
    int nx2 = (base + 2 < NBINS) ? s_h[base + 2] : 0;
    if (sv >= target && nx  < target) shv[0] = base;       // unique boundary
    if (nx >= target && nx2 < target) shv[0] = base + 1;
  }
  // scatter counters: base slot = suffix[bin+1]
  s_ctr[base]     = s_h[base + 1];
  s_ctr[base + 1] = (base + 2 < NBINS) ? s_h[base + 2] : 0;
  if (t >= nvalid && t < 300) {
    size_t bi = ((size_t)(b * 300 + t)) * 4;
    boxesWs[bi + 0] = 0.0f; boxesWs[bi + 1] = 0.0f;
    boxesWs[bi + 2] = 0.0f; boxesWs[bi + 3] = 0.0f;
  }
  if (t < 5) {
    int n = nvalid - t * 64;
    keepw[t] = (n <= 0) ? 0ULL : (n >= 64 ? ~0ULL : ((1ULL << n) - 1ULL));
  }
  __syncthreads();
  int T = shv[0];
  int Kslots = (T < NBINS) ? s_h[T] : 0;

  // one conf scan: scatter candidates with bin >= T into bin segments
  {
    const float4* cf4 = (const float4*)(conf + (size_t)b * NANCH);
    const int N4 = NANCH >> 2;                 // 6375 exactly
    float* cv = cand_v + (size_t)b * NANCH;
    int*   ci = cand_i + (size_t)b * NANCH;
    if (total > 0) {
      for (int i4 = t; i4 < N4; i4 += 1024) {
        float4 v4 = cf4[i4];
        int i0 = i4 * 4;
        float vv[4] = {v4.x, v4.y, v4.z, v4.w};
        #pragma unroll
        for (int q = 0; q < 4; ++q) {
          float v = vv[q];
          if (v > 0.1f) {
            int bin = conf_bin(v);
            if (bin >= T) {
              int slot = atomicAdd(&s_ctr[bin], 1);
              if (slot < CAP) { lv_s[slot] = v; li_s[slot] = i0 + q; }
              else            { cv[slot] = v;   ci[slot] = i0 + q;   } // spill
            }
          }
        }
      }
    }
  }
  __syncthreads();

  // exact rank within bin segment + gather survivor boxes from preds
  {
    const float* cv = cand_v + (size_t)b * NANCH;
    const int*   ci = cand_i + (size_t)b * NANCH;
    for (int sIdx = t; sIdx < Kslots; sIdx += 1024) {
      float v; int id;
      if (sIdx < CAP) { v = lv_s[sIdx]; id = li_s[sIdx]; }
      else            { v = cv[sIdx];   id = ci[sIdx];   }
      int bin = conf_bin(v);
      int lo = (bin + 1 < NBINS) ? s_h[bin + 1] : 0;
      int hi = s_h[bin];
      int rank = lo;
      for (int j = lo; j < hi; ++j) {
        float vj; int ij;
        if (j < CAP) { vj = lv_s[j]; ij = li_s[j]; }
        else         { vj = cv[j];   ij = ci[j];   }
        rank += (int)((vj > v) | ((vj == v) & (ij < id)));
      }
      if (rank < 300) {
        const float* p = preds + ((size_t)b * NANCH + id) * 85;
        float cx = p[0], cy = p[1], w = p[2], h = p[3];
        float hw2 = w * 0.5f, hh2 = h * 0.5f;
        float x1 = cx - hw2, y1 = cy - hh2, x2 = cx + hw2, y2 = cy + hh2;
        bxx[rank][0] = x1; bxx[rank][1] = y1; bxx[rank][2] = x2; bxx[rank][3] = y2;
        size_t bi = ((size_t)(b * 300 + rank)) * 4;
        boxesWs[bi + 0] = x1; boxesWs[bi + 1] = y1;
        boxesWs[bi + 2] = x2; boxesWs[bi + 3] = y2;
        int c = clsg[(size_t)b * NANCH + id];
        float off = (float)c * 4096.0f;
        float4 ob; ob.x = x1 + off; ob.y = y1 + off; ob.z = x2 + off; ob.w = y2 + off;
        bo4[rank] = ob;
      }
    }
  }
  __syncthreads();

  // IOU ballot mask: 10 waves; one ds_read_b128 broadcast per row
  {
    int wv = t >> 6, ln = t & 63;
    if (wv < 10) {
      int w = wv >> 1, half = wv & 1;
      int j = w * 64 + ln;
      int jc = j < 300 ? j : 0;
      float4 jb = bo4[jc];
      float ja = (jb.z - jb.x) * (jb.w - jb.y);
      bool jv = j < 300;
      int iend = w * 64 + 64; if (iend > 300) iend = 300;
      int i0 = half * 150, i1 = i0 + 150; if (i1 > iend) i1 = iend;
      #pragma unroll 4
      for (int i = i0; i < i1; ++i) {
        float4 ib = bo4[i];
        float ai = (ib.z - ib.x) * (ib.w - ib.y);
        float ltx = fmaxf(ib.x, jb.x);
        float lty = fmaxf(ib.y, jb.y);
        float rbx = fminf(ib.z, jb.z);
        float rby = fminf(ib.w, jb.w);
        float wx = fmaxf(rbx - ltx, 0.0f);
        float wy = fmaxf(rby - lty, 0.0f);
        float inter = wx * wy;
        float iou = inter / (ai + ja - inter + 1e-7f);
        ull bal = __ballot(jv && (j > i) && (iou > 0.6f));
        if (ln == 0) {
          mask[i][w] = bal;
          if (bal) atomicOr(&nzrow[i >> 6], 1ULL << (i & 63));
        }
      }
    }
  }
  __syncthreads();
  if (t == 0) {
    ull kw[5], nz[5];
    #pragma unroll
    for (int w = 0; w < 5; ++w) { kw[w] = keepw[w]; nz[w] = nzrow[w]; }
    #pragma unroll
    for (int w = 0; w < 5; ++w) {
      ull p = kw[w] & nz[w];
      while (p) {
        int l = __builtin_ctzll(p);
        p &= p - 1;
        int i = w * 64 + l;
        for (int w2 = w; w2 < 5; ++w2) {
          ull m = mask[i][w2];
          kw[w2] &= ~m;
          if (w2 == w) p &= ~m;
        }
      }
    }
    #pragma unroll
    for (int w = 0; w < 5; ++w) keepw[w] = kw[w];
  }
  __syncthreads();
  if (t < 300) {
    int kp = (int)((keepw[t >> 6] >> (t & 63)) & 1ULL);
    keepWs[b * 300 + t] = kp;
    float oh = orig_hw[b * 2 + 0], ow = orig_hw[b * 2 + 1];
    float gain = fminf(640.0f / oh, 640.0f / ow);
    float padx = (640.0f - ow * gain) * 0.5f;
    float pady = (640.0f - oh * gain) * 0.5f;
    float x1 = fminf(fmaxf((bxx[t][0] - padx) / gain, 0.0f), ow) / ow;
    float y1 = fminf(fmaxf((bxx[t][1] - pady) / gain, 0.0f), oh) / oh;
    float x2 = fminf(fmaxf((bxx[t][2] - padx) / gain, 0.0f), ow) / ow;
    float y2 = fminf(fmaxf((bxx[t][3] - pady) / gain, 0.0f), oh) / oh;
    size_t o = ((size_t)(b * 300 + t)) * 260;
    out[o + 0] = kp ? x1 : 0.0f;
    out[o + 1] = kp ? y1 : 0.0f;
    out[o + 2] = kp ? x2 : 0.0f;
    out[o + 3] = kp ? y2 : 0.0f;
  }
}

// ---------------------------------------------------------------------------
// K4: ROI-align 1x1 over 4 levels from HWC bf16 features -> bf16 fmat rows.
// XCD-affinity: b = blockIdx.x & 7 so every block of batch b lands on XCD b.
// ---------------------------------------------------------------------------
__global__ __launch_bounds__(256) void roi_kernel(const float* __restrict__ boxes,
                                                  const __hip_bfloat16* __restrict__ fT1, const __hip_bfloat16* __restrict__ fT2,
                                                  const __hip_bfloat16* __restrict__ fT3, const __hip_bfloat16* __restrict__ fT4,
                                                  __hip_bfloat16* __restrict__ f) {
  int b = blockIdx.x & 7;
  int r = blockIdx.x >> 3;
  __shared__ int t_off[4][16];
  __shared__ float t_w[4][16];
  int t = threadIdx.x;
  const int Hs[4] = {80, 40, 20, 10};
  const int Cs[4] = {128, 256, 512, 1024};
  const float ss[4] = {0.125f, 0.0625f, 0.03125f, 0.015625f};
  size_t bbase = ((size_t)(b * 300 + r)) * 4;
  float bx0 = boxes[bbase + 0];
  float by0 = boxes[bbase + 1];
  float bx1 = boxes[bbase + 2];
  float by1 = boxes[bbase + 3];
  if (t < 64) {
    int lv = t >> 4, k = t & 15, pp = k >> 2, nb = k & 3;
    float s = ss[lv];
    int H = Hs[lv], W = Hs[lv], C = Cs[lv];
    float b0 = bx0 * s, b1 = by0 * s, b2 = bx1 * s, b3 = by1 * s;
    float w = fmaxf(b2 - b0, 1.0f), h = fmaxf(b3 - b1, 1.0f);
    const float offv[2] = {0.5f, 1.5f};
    float px = b0 + offv[pp & 1] * (w * 0.5f);
    float py = b1 + offv[pp >> 1] * (h * 0.5f);
    float y = fminf(fmaxf(py, 0.0f), (float)(H - 1));
    float x = fminf(fmaxf(px, 0.0f), (float)(W - 1));
    int y0 = (int)floorf(y), x0 = (int)floorf(x);
    int y1 = min(y0 + 1, H - 1), x1 = min(x0 + 1, W - 1);
    float ly = y - (float)y0, lx = x - (float)x0;
    int yy = (nb & 2) ? y1 : y0;
    int xx = (nb & 1) ? x1 : x0;
    float wy = (nb & 2) ? ly : (1.0f - ly);
    float wx = (nb & 1) ? lx : (1.0f - lx);
    t_off[lv][k] = (yy * W + xx) * C;
    t_w[lv][k] = wy * wx;
  }
  __syncthreads();
  const __hip_bfloat16* bases[4] = {
    fT1 + (size_t)b * 6400 * 128,
    fT2 + (size_t)b * 1600 * 256,
    fT3 + (size_t)b * 400 * 512,
    fT4 + (size_t)b * 100 * 1024
  };
  __hip_bfloat16* frow = f + (size_t)(b * 300 + r) * 1920;
  int cbase = 0;
  #pragma unroll
  for (int lv = 0; lv < 4; ++lv) {
    int C = Cs[lv];
    const __hip_bfloat16* base = bases[lv];
    for (int c = t; c < C; c += 256) {
      float acc = 0.0f;
      #pragma unroll
      for (int k = 0; k < 16; ++k)
        acc += t_w[lv][k] * __bfloat162float(base[t_off[lv][k] + c]);
      frow[cbase + c] = __float2bfloat16(acc * 0.25f);
    }
    cbase += C;
  }
}

// ---------------------------------------------------------------------------
// K5/K6: staged bf16 MFMA GEMM. BM=BN=BK=64, 4 waves/block (each 32x32),
// double-buffered LDS via global_load_lds(16B) with both-sides XOR swizzle.
// ---------------------------------------------------------------------------
#define GLDS16(gp, lp) __builtin_amdgcn_global_load_lds( \
    (const __attribute__((address_space(1))) unsigned int*)(gp), \
    (__attribute__((address_space(3))) unsigned int*)(lp), 16, 0, 0)

__global__ __launch_bounds__(256) void gemm_tile_kernel(const __hip_bfloat16* __restrict__ A,
                                                        const __hip_bfloat16* __restrict__ BT,
                                                        const float* __restrict__ bias,
                                                        __hip_bfloat16* __restrict__ Cb,
                                                        float* __restrict__ Cf,
                                                        const int* __restrict__ keep,
                                                        int M, int N, int K, int ldc, int coff) {
  __shared__ __hip_bfloat16 sA[2][64 * 64];
  __shared__ __hip_bfloat16 sB[2][64 * 64];
  int tid = threadIdx.x;
  int bm = blockIdx.x * 64, bn = blockIdx.y * 64;
  int wave = tid >> 6, lane = tid & 63;
  int wr = wave >> 1, wc = wave & 1;
  int idx16 = lane & 15, kb = lane >> 4;
  floatx4 acc[2][2] = {};
  int nt = K >> 6;

  auto stage = [&](int buf, int t) {
    int k0 = t << 6;
    #pragma unroll
    for (int i = 0; i < 2; ++i) {
      int c = tid + i * 256;
      int row = c >> 3, cc = c & 7;
      int scc = cc ^ (row & 7);
      GLDS16(A + (size_t)(bm + row) * K + k0 + scc * 8,
             (char*)&sA[buf][0] + c * 16);
    }
    #pragma unroll
    for (int i = 0; i < 2; ++i) {
      int c = tid + i * 256;
      int row = c >> 3, cc = c & 7;
      int scc = cc ^ (row & 7);
      GLDS16(BT + (size_t)(bn + row) * K + k0 + scc * 8,
             (char*)&sB[buf][0] + c * 16);
    }
  };

  stage(0, 0);
  asm volatile("s_waitcnt vmcnt(0)" ::: "memory");
  __syncthreads();
  int cur = 0;
  for (int t = 0; t < nt; ++t) {
    if (t + 1 < nt) stage(cur ^ 1, t + 1);
    const char* Ab = (const char*)&sA[cur][0];
    const char* Bb = (const char*)&sB[cur][0];
    #pragma unroll
    for (int s = 0; s < 2; ++s) {
      bf16x8 af[2], bg[2];
      #pragma unroll
      for (int m = 0; m < 2; ++m) {
        int row = wr * 32 + m * 16 + idx16;
        int chunk = s * 4 + kb;
        af[m] = *(const bf16x8*)(Ab + row * 128 + ((chunk ^ (row & 7)) * 16));
      }
      #pragma unroll
      for (int n = 0; n < 2; ++n) {
        int row = wc * 32 + n * 16 + idx16;
        int chunk = s * 4 + kb;
        bg[n] = *(const bf16x8*)(Bb + row * 128 + ((chunk ^ (row & 7)) * 16));
      }
      #pragma unroll
      for (int m = 0; m < 2; ++m)
        #pragma unroll
        for (int n = 0; n < 2; ++n)
          acc[m][n] = __builtin_amdgcn_mfma_f32_16x16x32_bf16(af[m], bg[n], acc[m][n], 0, 0, 0);
    }
    asm volatile("s_waitcnt vmcnt(0)" ::: "memory");
    __syncthreads();
    cur ^= 1;
  }
  int col = lane & 15, rb4 = (lane >> 4) * 4;
  #pragma unroll
  for (int m = 0; m < 2; ++m) {
    #pragma unroll
    for (int n = 0; n < 2; ++n) {
      #pragma unroll
      for (int r = 0; r < 4; ++r) {
        int orow = bm + wr * 32 + m * 16 + rb4 + r;
        int ocol = bn + wc * 32 + n * 16 + col;
        if (orow >= M) continue;
        float v = acc[m][n][r] + bias[ocol];
        v = (v >= 0.0f) ? v : 0.01f * v;
        if (Cb) Cb[(size_t)orow * N + ocol] = __float2bfloat16(v);
        if (Cf) {
          float km = keep ? (keep[orow] ? 1.0f : 0.0f) : 1.0f;
          Cf[(size_t)orow * ldc + coff + ocol] = v * km;
        }
      }
    }
  }
}

// ---------------------------------------------------------------------------
extern "C" void kernel_launch(void* const* d_in, const int* in_sizes, int n_in,
                              void* d_out, int out_size, void* d_ws, size_t ws_size,
                              hipStream_t stream) {
  (void)in_sizes; (void)n_in; (void)out_size; (void)ws_size;
  const float* preds  = (const float*)d_in[0];
  const float* feat1  = (const float*)d_in[1];
  const float* feat2  = (const float*)d_in[2];
  const float* feat3  = (const float*)d_in[3];
  const float* feat4  = (const float*)d_in[4];
  const float* orighw = (const float*)d_in[5];
  const float* W1     = (const float*)d_in[6];
  const float* b1     = (const float*)d_in[7];
  const float* W2     = (const float*)d_in[8];
  const float* b2     = (const float*)d_in[9];
  float* out = (float*)d_out;

  char* ws = (char*)d_ws;
  size_t off = 0;
  auto alloc = [&](size_t bytes) -> void* {
    void* p = ws + off;
    off = (off + bytes + 255) & ~(size_t)255;
    return p;
  };
  const int BN = NBATCH * NANCH;   // 204000
  float*  conf   = (float*)alloc((size_t)BN * 4);
  int*    cls    = (int*)  alloc((size_t)BN * 4);
  float*  cand_v = (float*)alloc((size_t)BN * 4);
  int*    cand_i = (int*)  alloc((size_t)BN * 4);
  int*    ghist  = (int*)  alloc((size_t)NBATCH * NBINS * 4);
  float*  boxes  = (float*)alloc((size_t)NBATCH * 300 * 4 * 4);
  int*    keep   = (int*)  alloc((size_t)NBATCH * 300 * 4);
  __hip_bfloat16* fT1  = (__hip_bfloat16*)alloc((size_t)NBATCH * 6400 * 128 * 2);
  __hip_bfloat16* fT2  = (__hip_bfloat16*)alloc((size_t)NBATCH * 1600 * 256 * 2);
  __hip_bfloat16* fT3  = (__hip_bfloat16*)alloc((size_t)NBATCH * 400 * 512 * 2);
  __hip_bfloat16* fT4  = (__hip_bfloat16*)alloc((size_t)NBATCH * 100 * 1024 * 2);
  __hip_bfloat16* fmat = (__hip_bfloat16*)alloc((size_t)2400 * 1920 * 2);
  __hip_bfloat16* h1b  = (__hip_bfloat16*)alloc((size_t)2400 * 256 * 2);
  __hip_bfloat16* W1T  = (__hip_bfloat16*)alloc((size_t)256 * 1920 * 2);
  __hip_bfloat16* W2T  = (__hip_bfloat16*)alloc((size_t)256 * 256 * 2);

  conf_kernel<<<(BN + CONF_TILE - 1) / CONF_TILE, 256, 0, stream>>>(preds, conf, cls, ghist, BN);

  // 64 histogram blocks first (overlap), then fused transposes
  TransArgs ta;
  ta.src[0] = feat1; ta.dst[0] = fT1; ta.C[0] = 128;  ta.HW[0] = 6400; ta.tx[0] = 200;
  ta.src[1] = feat2; ta.dst[1] = fT2; ta.C[1] = 256;  ta.HW[1] = 1600; ta.tx[1] = 50;
  ta.src[2] = feat3; ta.dst[2] = fT3; ta.C[2] = 512;  ta.HW[2] = 400;  ta.tx[2] = 13;
  ta.src[3] = feat4; ta.dst[3] = fT4; ta.C[3] = 1024; ta.HW[3] = 100;  ta.tx[3] = 4;
  ta.src[4] = W1;    ta.dst[4] = W1T; ta.C[4] = 1920; ta.HW[4] = 256;  ta.tx[4] = 8;
  ta.src[5] = W2;    ta.dst[5] = W2T; ta.C[5] = 256;  ta.HW[5] = 256;  ta.tx[5] = 8;
  int total_blocks = 0;
  for (int s = 0; s < 6; ++s) {
    int ty = (ta.C[s] + 31) / 32;
    int nbatch = (s < 4) ? NBATCH : 1;
    ta.tpb[s] = ta.tx[s] * ty;
    ta.start[s] = total_blocks;
    total_blocks += ta.tpb[s] * nbatch;
  }
  transpose_all_kernel<<<total_blocks + 64, dim3(32, 8), 0, stream>>>(ta, conf, ghist);

  nms_kernel<<<NBATCH, 1024, 0, stream>>>(conf, preds, cls, ghist, cand_v, cand_i,
                                          boxes, keep, orighw, out);
  roi_kernel<<<2400, 256, 0, stream>>>(boxes, fT1, fT2, fT3, fT4, fmat);
  gemm_tile_kernel<<<dim3(38, 4), 256, 0, stream>>>(fmat, W1T, b1, h1b, nullptr, nullptr,
                                                    2400, 256, 1920, 0, 0);
  gemm_tile_kernel<<<dim3(38, 4), 256, 0, stream>>>(h1b, W2T, b2, nullptr, out, keep,
                                                    2400, 256, 256, 260, 4);
}

// Round 4
// 118.519 us; speedup vs baseline: 1.3042x; 1.1246x over previous
//
#include <hip/hip_runtime.h>
#include <hip/hip_bf16.h>
#include <cstdint>
#include <cstddef>

#define NBATCH 8
#define NANCH 25500
#define MAXDET 300
#define NBINS 2048
#define CAP 2048

typedef __bf16 bf16x8 __attribute__((ext_vector_type(8)));
typedef float floatx4 __attribute__((ext_vector_type(4)));
typedef unsigned long long ull;

__device__ __forceinline__ int conf_bin(float v) {
  unsigned bits = __float_as_uint(v);
  int bin = (int)((bits - 0x3D800000u) >> 14);   // [0.0625,1.0) -> 0..2047
  return bin > (NBINS - 1) ? (NBINS - 1) : bin;
}

// ---------------------------------------------------------------------------
// K1: conf = max_c(cls_c * obj), argmax class, threshold 0.1.
// Blocks 0..15 also zero ghist (8 x 2048 ints); block 16 zeros the done-ctr.
// ---------------------------------------------------------------------------
#define CONF_TILE 64
__global__ __launch_bounds__(256) void conf_kernel(const float* __restrict__ preds,
                                                   float* __restrict__ conf,
                                                   int* __restrict__ cls,
                                                   int* __restrict__ ghist,
                                                   int* __restrict__ ctr, int total) {
  if (blockIdx.x < 16) {
    #pragma unroll
    for (int k = 0; k < 4; ++k)
      ghist[blockIdx.x * 1024 + k * 256 + threadIdx.x] = 0;
  }
  if (blockIdx.x == 16 && threadIdx.x == 0) ctr[0] = 0;
  __shared__ float s[CONF_TILE * 85];
  int base = blockIdx.x * CONF_TILE;
  int nA = total - base; if (nA > CONF_TILE) nA = CONF_TILE;
  int n4 = (nA * 85) >> 2;
  const float4* g4 = (const float4*)(preds + (size_t)base * 85);
  float4* s4 = (float4*)s;
  for (int i = threadIdx.x; i < n4; i += 256) s4[i] = g4[i];
  __syncthreads();
  int lane16 = threadIdx.x & 15;
  int sub = threadIdx.x >> 4;
  #pragma unroll
  for (int r = 0; r < 4; ++r) {
    int a = r * 16 + sub;
    if (a < nA) {
      const float* row = s + a * 85;
      float obj = row[4];
      float best = -1.0f; int bc = 0;
      #pragma unroll
      for (int j = 0; j < 5; ++j) {
        int c = lane16 * 5 + j;
        float v = row[5 + c] * obj;    // exact IEEE mul, matches reference
        if (v > best) { best = v; bc = c; }
      }
      #pragma unroll
      for (int m = 1; m < 16; m <<= 1) {
        float ov = __shfl_xor(best, m, 64);
        int   oc = __shfl_xor(bc,   m, 64);
        if (ov > best || (ov == best && oc < bc)) { best = ov; bc = oc; }
      }
      if (lane16 == 0) {
        int idx = base + a;
        conf[idx] = (best > 0.1f) ? best : 0.0f;
        cls[idx] = bc;
      }
    }
  }
}

// ---------------------------------------------------------------------------
// K2 (fused mid kernel, 1024 threads as dim3(32,32)):
//  blocks 0..7   : per-batch NMS. Spin on done-ctr (hist blocks), then
//                  4-wave register suffix-scan of the 2048-bin hist (atomic
//                  loads -> shfl suffix, 2 barriers), threshold bin T for
//                  exact top-300, one conf scan scattering candidates into
//                  LDS bin segments, exact within-bin rank, gather boxes
//                  from preds, float4-IOU ballot NMS, ctz suppression,
//                  rescale, out cols 0..3. fp contract OFF (bit-exact IOU).
//  blocks 8..71  : per (batch, 1/8-segment) 2048-bin LDS hist of conf,
//                  flushed via global atomics, then fence + ctr bump.
//  blocks 72..   : fused (C,HW)->(HW,C) fp32->bf16 transposes; 4 of the old
//                  32x32 tiles per block (threadIdx.y>>3 selects sub-tile).
// NMS<->hist sync is via device-scope atomics only; deadlock-free (8
// spinners << 256 CUs). Total order undefined => spin, not assumption.
// ---------------------------------------------------------------------------
struct TransArgs {
  const float* src[6];
  __hip_bfloat16* dst[6];
  int C[6], HW[6], tx[6], tpb[6], start[6];   // start/tpb in TILE units
};

__global__ __launch_bounds__(1024) void mid_kernel(TransArgs a,
                                                   const float* __restrict__ conf,
                                                   const float* __restrict__ preds,
                                                   const int* __restrict__ clsg,
                                                   int* __restrict__ ghist,
                                                   int* __restrict__ ctr,
                                                   float* __restrict__ cand_v, int* __restrict__ cand_i,
                                                   float* __restrict__ boxesWs, int* __restrict__ keepWs,
                                                   const float* __restrict__ orig_hw,
                                                   float* __restrict__ out,
                                                   int n_trans_tiles) {
  #pragma clang fp contract(off)
  __shared__ __align__(16) char smem[42496];
  int bid = blockIdx.x;
  int t = threadIdx.y * 32 + threadIdx.x;

  if (bid < 8) {
    // =========================== NMS role ================================
    int b = bid;
    // LDS layout (phases are barrier-separated):
    //  s_h   @0     (8192)  inclusive suffix array (dead after rank)
    //  s_ctr @8192  (8192)  scatter counters (dead after scatter)
    //  mask  @0     (12000) IOU phase overlay of s_h+s_ctr
    //  lv_s  @16384 (8192), li_s @24576 (8192)  candidates
    //  bo4   @32768 (4800), bxx @37568 (4800)
    //  keepw @42368, nzrow @42408, shv @42448 (12 ints)
    int*    s_h  = (int*)smem;
    int*    s_ctr= (int*)(smem + 8192);
    ull   (*mask)[5] = (ull(*)[5])smem;
    float*  lv_s = (float*)(smem + 16384);
    int*    li_s = (int*)(smem + 24576);
    float4* bo4  = (float4*)(smem + 32768);
    float (*bxx)[4] = (float(*)[4])(smem + 37568);
    ull* keepw = (ull*)(smem + 42368);
    ull* nzrow = (ull*)(smem + 42408);
    int* shv   = (int*)(smem + 42448);   // [0]=T [1]=total [2]=Kslots [4..7]=wave part sums

    if (t < 300) {
      bo4[t] = make_float4(0.0f, 0.0f, 0.0f, 0.0f);
      bxx[t][0] = 0.0f; bxx[t][1] = 0.0f; bxx[t][2] = 0.0f; bxx[t][3] = 0.0f;
    }
    if (t < 5) nzrow[t] = 0ULL;
    if (t == 1) { shv[0] = NBINS; shv[2] = 0; }
    if (t == 0) {
      while (atomicAdd(ctr, 0) < 64) __builtin_amdgcn_s_sleep(8);
      __threadfence();
    }
    __syncthreads();

    // ---- 4-wave register suffix scan over 2048 bins ----
    int r[8], suf[8], rs[8];
    int w = t >> 6, lane = t & 63;
    if (t < 256) {
      #pragma unroll
      for (int k = 0; k < 8; ++k)
        r[k] = atomicAdd(&ghist[b * NBINS + (w * 8 + k) * 64 + lane], 0);
      int bsum = 0;
      #pragma unroll
      for (int k = 0; k < 8; ++k) {
        int s = r[k];
        #pragma unroll
        for (int d = 1; d < 64; d <<= 1) {
          int o = __shfl_down(s, d, 64);
          if (lane + d < 64) s += o;
        }
        suf[k] = s - r[k];              // sum over lanes > lane, same row
        rs[k] = __shfl(s, 0, 64);       // row total
        bsum += rs[k];
      }
      if (lane == 0) shv[4 + w] = bsum;
    }
    __syncthreads();
    if (t < 256) {
      int p1 = shv[5], p2 = shv[6], p3 = shv[7];
      int total = shv[4] + p1 + p2 + p3;
      int target = total < 300 ? total : 300;
      int RS = (w == 0) ? (p1 + p2 + p3) : (w == 1) ? (p2 + p3) : (w == 2) ? p3 : 0;
      int run = RS;
      #pragma unroll
      for (int k = 7; k >= 0; --k) {
        int Sx = run + suf[k] + r[k];    // suffix[bin] inclusive
        int Sx1 = Sx - r[k];             // suffix[bin+1]
        int bin = (w * 8 + k) * 64 + lane;
        s_h[bin] = Sx;
        s_ctr[bin] = Sx1;                // scatter base
        if (total > 0 && Sx >= target && Sx1 < target) { shv[0] = bin; shv[2] = Sx; }
        run += rs[k];
      }
      if (t == 0) shv[1] = total;
    }
    __syncthreads();
    int T = shv[0];
    int total = shv[1];
    int Kslots = shv[2];
    int nvalid = total < 300 ? total : 300;

    if (t >= nvalid && t < 300) {
      size_t bi = ((size_t)(b * 300 + t)) * 4;
      boxesWs[bi + 0] = 0.0f; boxesWs[bi + 1] = 0.0f;
      boxesWs[bi + 2] = 0.0f; boxesWs[bi + 3] = 0.0f;
    }
    if (t < 5) {
      int n = nvalid - t * 64;
      keepw[t] = (n <= 0) ? 0ULL : (n >= 64 ? ~0ULL : ((1ULL << n) - 1ULL));
    }

    // ---- one conf scan: scatter candidates with bin >= T ----
    {
      const float4* cf4 = (const float4*)(conf + (size_t)b * NANCH);
      const int N4 = NANCH >> 2;                 // 6375 exactly
      float* cv = cand_v + (size_t)b * NANCH;
      int*   ci = cand_i + (size_t)b * NANCH;
      if (total > 0) {
        for (int i4 = t; i4 < N4; i4 += 1024) {
          float4 v4 = cf4[i4];
          int i0 = i4 * 4;
          float vv[4] = {v4.x, v4.y, v4.z, v4.w};
          #pragma unroll
          for (int q = 0; q < 4; ++q) {
            float v = vv[q];
            if (v > 0.1f) {
              int bin = conf_bin(v);
              if (bin >= T) {
                int slot = atomicAdd(&s_ctr[bin], 1);
                if (slot < CAP) { lv_s[slot] = v; li_s[slot] = i0 + q; }
                else            { cv[slot] = v;   ci[slot] = i0 + q;   } // spill
              }
            }
          }
        }
      }
    }
    __syncthreads();

    // ---- exact rank within bin segment + gather survivor boxes ----
    {
      const float* cv = cand_v + (size_t)b * NANCH;
      const int*   ci = cand_i + (size_t)b * NANCH;
      for (int sIdx = t; sIdx < Kslots; sIdx += 1024) {
        float v; int id;
        if (sIdx < CAP) { v = lv_s[sIdx]; id = li_s[sIdx]; }
        else            { v = cv[sIdx];   id = ci[sIdx];   }
        int bin = conf_bin(v);
        int lo = (bin + 1 < NBINS) ? s_h[bin + 1] : 0;
        int hi = s_h[bin];
        int rank = lo;
        for (int j = lo; j < hi; ++j) {
          float vj; int ij;
          if (j < CAP) { vj = lv_s[j]; ij = li_s[j]; }
          else         { vj = cv[j];   ij = ci[j];   }
          rank += (int)((vj > v) | ((vj == v) & (ij < id)));
        }
        if (rank < 300) {
          const float* p = preds + ((size_t)b * NANCH + id) * 85;
          float cx = p[0], cy = p[1], wq = p[2], hq = p[3];
          float hw2 = wq * 0.5f, hh2 = hq * 0.5f;
          float x1 = cx - hw2, y1 = cy - hh2, x2 = cx + hw2, y2 = cy + hh2;
          bxx[rank][0] = x1; bxx[rank][1] = y1; bxx[rank][2] = x2; bxx[rank][3] = y2;
          size_t bi = ((size_t)(b * 300 + rank)) * 4;
          boxesWs[bi + 0] = x1; boxesWs[bi + 1] = y1;
          boxesWs[bi + 2] = x2; boxesWs[bi + 3] = y2;
          int c = clsg[(size_t)b * NANCH + id];
          float off = (float)c * 4096.0f;
          float4 ob; ob.x = x1 + off; ob.y = y1 + off; ob.z = x2 + off; ob.w = y2 + off;
          bo4[rank] = ob;
        }
      }
    }
    __syncthreads();

    // ---- IOU ballot mask: 10 waves; one ds_read_b128 broadcast per row ----
    {
      int wv = t >> 6, ln = t & 63;
      if (wv < 10) {
        int w2 = wv >> 1, half = wv & 1;
        int j = w2 * 64 + ln;
        int jc = j < 300 ? j : 0;
        float4 jb = bo4[jc];
        float ja = (jb.z - jb.x) * (jb.w - jb.y);
        bool jv = j < 300;
        int iend = w2 * 64 + 64; if (iend > 300) iend = 300;
        int i0 = half * 150, i1 = i0 + 150; if (i1 > iend) i1 = iend;
        #pragma unroll 4
        for (int i = i0; i < i1; ++i) {
          float4 ib = bo4[i];
          float ai = (ib.z - ib.x) * (ib.w - ib.y);
          float ltx = fmaxf(ib.x, jb.x);
          float lty = fmaxf(ib.y, jb.y);
          float rbx = fminf(ib.z, jb.z);
          float rby = fminf(ib.w, jb.w);
          float wx = fmaxf(rbx - ltx, 0.0f);
          float wy = fmaxf(rby - lty, 0.0f);
          float inter = wx * wy;
          float iou = inter / (ai + ja - inter + 1e-7f);
          ull bal = __ballot(jv && (j > i) && (iou > 0.6f));
          if (ln == 0) {
            mask[i][w2] = bal;
            if (bal) atomicOr(&nzrow[i >> 6], 1ULL << (i & 63));
          }
        }
      }
    }
    __syncthreads();
    if (t == 0) {
      ull kw[5], nz[5];
      #pragma unroll
      for (int w2 = 0; w2 < 5; ++w2) { kw[w2] = keepw[w2]; nz[w2] = nzrow[w2]; }
      #pragma unroll
      for (int w2 = 0; w2 < 5; ++w2) {
        ull p = kw[w2] & nz[w2];
        while (p) {
          int l = __builtin_ctzll(p);
          p &= p - 1;
          int i = w2 * 64 + l;
          for (int w3 = w2; w3 < 5; ++w3) {
            ull m = mask[i][w3];
            kw[w3] &= ~m;
            if (w3 == w2) p &= ~m;
          }
        }
      }
      #pragma unroll
      for (int w2 = 0; w2 < 5; ++w2) keepw[w2] = kw[w2];
    }
    __syncthreads();
    if (t < 300) {
      int kp = (int)((keepw[t >> 6] >> (t & 63)) & 1ULL);
      keepWs[b * 300 + t] = kp;
      float oh = orig_hw[b * 2 + 0], ow = orig_hw[b * 2 + 1];
      float gain = fminf(640.0f / oh, 640.0f / ow);
      float padx = (640.0f - ow * gain) * 0.5f;
      float pady = (640.0f - oh * gain) * 0.5f;
      float x1 = fminf(fmaxf((bxx[t][0] - padx) / gain, 0.0f), ow) / ow;
      float y1 = fminf(fmaxf((bxx[t][1] - pady) / gain, 0.0f), oh) / oh;
      float x2 = fminf(fmaxf((bxx[t][2] - padx) / gain, 0.0f), ow) / ow;
      float y2 = fminf(fmaxf((bxx[t][3] - pady) / gain, 0.0f), oh) / oh;
      size_t o = ((size_t)(b * 300 + t)) * 260;
      out[o + 0] = kp ? x1 : 0.0f;
      out[o + 1] = kp ? y1 : 0.0f;
      out[o + 2] = kp ? x2 : 0.0f;
      out[o + 3] = kp ? y2 : 0.0f;
    }
    return;
  }

  if (bid < 72) {
    // =========================== hist role ===============================
    int hb = bid - 8;
    int b = hb >> 3, seg = hb & 7;
    int* sh = (int*)smem;                       // 2048 bins
    sh[t] = 0; sh[t + 1024] = 0;
    __syncthreads();
    const int N4 = NANCH >> 2;                  // 6375
    int i0 = (N4 * seg) >> 3, i1 = (N4 * (seg + 1)) >> 3;
    const float4* cf4 = (const float4*)(conf + (size_t)b * NANCH);
    for (int i = i0 + t; i < i1; i += 1024) {
      float4 v = cf4[i];
      if (v.x > 0.1f) atomicAdd(&sh[conf_bin(v.x)], 1);
      if (v.y > 0.1f) atomicAdd(&sh[conf_bin(v.y)], 1);
      if (v.z > 0.1f) atomicAdd(&sh[conf_bin(v.z)], 1);
      if (v.w > 0.1f) atomicAdd(&sh[conf_bin(v.w)], 1);
    }
    __syncthreads();
    {
      int c = sh[t];        if (c) atomicAdd(&ghist[b * NBINS + t], c);
      c     = sh[t + 1024]; if (c) atomicAdd(&ghist[b * NBINS + t + 1024], c);
    }
    __syncthreads();                            // all flush atomics drained
    if (t == 0) { __threadfence(); atomicAdd(ctr, 1); }
    return;
  }

  // ============================ transpose role ===========================
  {
    int sub = threadIdx.y >> 3;
    int tyl = threadIdx.y & 7, tx = threadIdx.x;
    int gt = (bid - 72) * 4 + sub;
    float (*tile)[33] = (float(*)[33])(smem + sub * 4224);
    int s = 0, local = 0, C = 0, HW = 0, p0 = 0, c0 = 0, bb = 0;
    const float* inb = nullptr;
    __hip_bfloat16* outb = nullptr;
    bool act = gt < n_trans_tiles;
    if (act) {
      #pragma unroll
      for (int i = 1; i < 6; ++i) if (gt >= a.start[i]) s = i;
      local = gt - a.start[s];
      C = a.C[s]; HW = a.HW[s];
      int tx0 = a.tx[s], tpb = a.tpb[s];
      bb = local / tpb;
      int rem = local - bb * tpb;
      p0 = (rem % tx0) * 32;
      c0 = (rem / tx0) * 32;
      inb = a.src[s] + (size_t)bb * C * HW;
      outb = a.dst[s] + (size_t)bb * C * HW;
      #pragma unroll
      for (int k = 0; k < 32; k += 8) {
        int c = c0 + tyl + k, p = p0 + tx;
        if (c < C && p < HW) tile[tyl + k][tx] = inb[(size_t)c * HW + p];
      }
    }
    __syncthreads();
    if (act) {
      #pragma unroll
      for (int k = 0; k < 32; k += 8) {
        int p = p0 + tyl + k, c = c0 + tx;
        if (p < HW && c < C) outb[(size_t)p * C + c] = __float2bfloat16(tile[tx][tyl + k]);
      }
    }
  }
}

// ---------------------------------------------------------------------------
// K4: ROI-align 1x1 over 4 levels from HWC bf16 features -> bf16 fmat rows.
// XCD-affinity: b = blockIdx.x & 7 so every block of batch b lands on XCD b.
// ---------------------------------------------------------------------------
__global__ __launch_bounds__(256) void roi_kernel(const float* __restrict__ boxes,
                                                  const __hip_bfloat16* __restrict__ fT1, const __hip_bfloat16* __restrict__ fT2,
                                                  const __hip_bfloat16* __restrict__ fT3, const __hip_bfloat16* __restrict__ fT4,
                                                  __hip_bfloat16* __restrict__ f) {
  int b = blockIdx.x & 7;
  int r = blockIdx.x >> 3;
  __shared__ int t_off[4][16];
  __shared__ float t_w[4][16];
  int t = threadIdx.x;
  const int Hs[4] = {80, 40, 20, 10};
  const int Cs[4] = {128, 256, 512, 1024};
  const float ss[4] = {0.125f, 0.0625f, 0.03125f, 0.015625f};
  size_t bbase = ((size_t)(b * 300 + r)) * 4;
  float bx0 = boxes[bbase + 0];
  float by0 = boxes[bbase + 1];
  float bx1 = boxes[bbase + 2];
  float by1 = boxes[bbase + 3];
  if (t < 64) {
    int lv = t >> 4, k = t & 15, pp = k >> 2, nb = k & 3;
    float s = ss[lv];
    int H = Hs[lv], W = Hs[lv], C = Cs[lv];
    float b0 = bx0 * s, b1 = by0 * s, b2 = bx1 * s, b3 = by1 * s;
    float w = fmaxf(b2 - b0, 1.0f), h = fmaxf(b3 - b1, 1.0f);
    const float offv[2] = {0.5f, 1.5f};
    float px = b0 + offv[pp & 1] * (w * 0.5f);
    float py = b1 + offv[pp >> 1] * (h * 0.5f);
    float y = fminf(fmaxf(py, 0.0f), (float)(H - 1));
    float x = fminf(fmaxf(px, 0.0f), (float)(W - 1));
    int y0 = (int)floorf(y), x0 = (int)floorf(x);
    int y1 = min(y0 + 1, H - 1), x1 = min(x0 + 1, W - 1);
    float ly = y - (float)y0, lx = x - (float)x0;
    int yy = (nb & 2) ? y1 : y0;
    int xx = (nb & 1) ? x1 : x0;
    float wy = (nb & 2) ? ly : (1.0f - ly);
    float wx = (nb & 1) ? lx : (1.0f - lx);
    t_off[lv][k] = (yy * W + xx) * C;
    t_w[lv][k] = wy * wx;
  }
  __syncthreads();
  const __hip_bfloat16* bases[4] = {
    fT1 + (size_t)b * 6400 * 128,
    fT2 + (size_t)b * 1600 * 256,
    fT3 + (size_t)b * 400 * 512,
    fT4 + (size_t)b * 100 * 1024
  };
  __hip_bfloat16* frow = f + (size_t)(b * 300 + r) * 1920;
  int cbase = 0;
  #pragma unroll
  for (int lv = 0; lv < 4; ++lv) {
    int C = Cs[lv];
    const __hip_bfloat16* base = bases[lv];
    for (int c = t; c < C; c += 256) {
      float acc = 0.0f;
      #pragma unroll
      for (int k = 0; k < 16; ++k)
        acc += t_w[lv][k] * __bfloat162float(base[t_off[lv][k] + c]);
      frow[cbase + c] = __float2bfloat16(acc * 0.25f);
    }
    cbase += C;
  }
}

// ---------------------------------------------------------------------------
// K5/K6: staged bf16 MFMA GEMM. BM=BN=BK=64, 4 waves/block (each 32x32),
// double-buffered LDS via global_load_lds(16B) with both-sides XOR swizzle.
// ---------------------------------------------------------------------------
#define GLDS16(gp, lp) __builtin_amdgcn_global_load_lds( \
    (const __attribute__((address_space(1))) unsigned int*)(gp), \
    (__attribute__((address_space(3))) unsigned int*)(lp), 16, 0, 0)

__global__ __launch_bounds__(256) void gemm_tile_kernel(const __hip_bfloat16* __restrict__ A,
                                                        const __hip_bfloat16* __restrict__ BT,
                                                        const float* __restrict__ bias,
                                                        __hip_bfloat16* __restrict__ Cb,
                                                        float* __restrict__ Cf,
                                                        const int* __restrict__ keep,
                                                        int M, int N, int K, int ldc, int coff) {
  __shared__ __hip_bfloat16 sA[2][64 * 64];
  __shared__ __hip_bfloat16 sB[2][64 * 64];
  int tid = threadIdx.x;
  int bm = blockIdx.x * 64, bn = blockIdx.y * 64;
  int wave = tid >> 6, lane = tid & 63;
  int wr = wave >> 1, wc = wave & 1;
  int idx16 = lane & 15, kb = lane >> 4;
  floatx4 acc[2][2] = {};
  int nt = K >> 6;

  auto stage = [&](int buf, int t) {
    int k0 = t << 6;
    #pragma unroll
    for (int i = 0; i < 2; ++i) {
      int c = tid + i * 256;
      int row = c >> 3, cc = c & 7;
      int scc = cc ^ (row & 7);
      GLDS16(A + (size_t)(bm + row) * K + k0 + scc * 8,
             (char*)&sA[buf][0] + c * 16);
    }
    #pragma unroll
    for (int i = 0; i < 2; ++i) {
      int c = tid + i * 256;
      int row = c >> 3, cc = c & 7;
      int scc = cc ^ (row & 7);
      GLDS16(BT + (size_t)(bn + row) * K + k0 + scc * 8,
             (char*)&sB[buf][0] + c * 16);
    }
  };

  stage(0, 0);
  asm volatile("s_waitcnt vmcnt(0)" ::: "memory");
  __syncthreads();
  int cur = 0;
  for (int t = 0; t < nt; ++t) {
    if (t + 1 < nt) stage(cur ^ 1, t + 1);
    const char* Ab = (const char*)&sA[cur][0];
    const char* Bb = (const char*)&sB[cur][0];
    #pragma unroll
    for (int s = 0; s < 2; ++s) {
      bf16x8 af[2], bg[2];
      #pragma unroll
      for (int m = 0; m < 2; ++m) {
        int row = wr * 32 + m * 16 + idx16;
        int chunk = s * 4 + kb;
        af[m] = *(const bf16x8*)(Ab + row * 128 + ((chunk ^ (row & 7)) * 16));
      }
      #pragma unroll
      for (int n = 0; n < 2; ++n) {
        int row = wc * 32 + n * 16 + idx16;
        int chunk = s * 4 + kb;
        bg[n] = *(const bf16x8*)(Bb + row * 128 + ((chunk ^ (row & 7)) * 16));
      }
      #pragma unroll
      for (int m = 0; m < 2; ++m)
        #pragma unroll
        for (int n = 0; n < 2; ++n)
          acc[m][n] = __builtin_amdgcn_mfma_f32_16x16x32_bf16(af[m], bg[n], acc[m][n], 0, 0, 0);
    }
    asm volatile("s_waitcnt vmcnt(0)" ::: "memory");
    __syncthreads();
    cur ^= 1;
  }
  int col = lane & 15, rb4 = (lane >> 4) * 4;
  #pragma unroll
  for (int m = 0; m < 2; ++m) {
    #pragma unroll
    for (int n = 0; n < 2; ++n) {
      #pragma unroll
      for (int r = 0; r < 4; ++r) {
        int orow = bm + wr * 32 + m * 16 + rb4 + r;
        int ocol = bn + wc * 32 + n * 16 + col;
        if (orow >= M) continue;
        float v = acc[m][n][r] + bias[ocol];
        v = (v >= 0.0f) ? v : 0.01f * v;
        if (Cb) Cb[(size_t)orow * N + ocol] = __float2bfloat16(v);
        if (Cf) {
          float km = keep ? (keep[orow] ? 1.0f : 0.0f) : 1.0f;
          Cf[(size_t)orow * ldc + coff + ocol] = v * km;
        }
      }
    }
  }
}

// ---------------------------------------------------------------------------
extern "C" void kernel_launch(void* const* d_in, const int* in_sizes, int n_in,
                              void* d_out, int out_size, void* d_ws, size_t ws_size,
                              hipStream_t stream) {
  (void)in_sizes; (void)n_in; (void)out_size; (void)ws_size;
  const float* preds  = (const float*)d_in[0];
  const float* feat1  = (const float*)d_in[1];
  const float* feat2  = (const float*)d_in[2];
  const float* feat3  = (const float*)d_in[3];
  const float* feat4  = (const float*)d_in[4];
  const float* orighw = (const float*)d_in[5];
  const float* W1     = (const float*)d_in[6];
  const float* b1     = (const float*)d_in[7];
  const float* W2     = (const float*)d_in[8];
  const float* b2     = (const float*)d_in[9];
  float* out = (float*)d_out;

  char* ws = (char*)d_ws;
  size_t off = 0;
  auto alloc = [&](size_t bytes) -> void* {
    void* p = ws + off;
    off = (off + bytes + 255) & ~(size_t)255;
    return p;
  };
  const int BN = NBATCH * NANCH;   // 204000
  float*  conf   = (float*)alloc((size_t)BN * 4);
  int*    cls    = (int*)  alloc((size_t)BN * 4);
  float*  cand_v = (float*)alloc((size_t)BN * 4);
  int*    cand_i = (int*)  alloc((size_t)BN * 4);
  int*    ghist  = (int*)  alloc((size_t)NBATCH * NBINS * 4);
  int*    ctr    = (int*)  alloc(256);
  float*  boxes  = (float*)alloc((size_t)NBATCH * 300 * 4 * 4);
  int*    keep   = (int*)  alloc((size_t)NBATCH * 300 * 4);
  __hip_bfloat16* fT1  = (__hip_bfloat16*)alloc((size_t)NBATCH * 6400 * 128 * 2);
  __hip_bfloat16* fT2  = (__hip_bfloat16*)alloc((size_t)NBATCH * 1600 * 256 * 2);
  __hip_bfloat16* fT3  = (__hip_bfloat16*)alloc((size_t)NBATCH * 400 * 512 * 2);
  __hip_bfloat16* fT4  = (__hip_bfloat16*)alloc((size_t)NBATCH * 100 * 1024 * 2);
  __hip_bfloat16* fmat = (__hip_bfloat16*)alloc((size_t)2400 * 1920 * 2);
  __hip_bfloat16* h1b  = (__hip_bfloat16*)alloc((size_t)2400 * 256 * 2);
  __hip_bfloat16* W1T  = (__hip_bfloat16*)alloc((size_t)256 * 1920 * 2);
  __hip_bfloat16* W2T  = (__hip_bfloat16*)alloc((size_t)256 * 256 * 2);

  conf_kernel<<<(BN + CONF_TILE - 1) / CONF_TILE, 256, 0, stream>>>(preds, conf, cls, ghist, ctr, BN);

  // fused mid kernel: 8 nms + 64 hist + transposes (4 tiles/block)
  TransArgs ta;
  ta.src[0] = feat1; ta.dst[0] = fT1; ta.C[0] = 128;  ta.HW[0] = 6400; ta.tx[0] = 200;
  ta.src[1] = feat2; ta.dst[1] = fT2; ta.C[1] = 256;  ta.HW[1] = 1600; ta.tx[1] = 50;
  ta.src[2] = feat3; ta.dst[2] = fT3; ta.C[2] = 512;  ta.HW[2] = 400;  ta.tx[2] = 13;
  ta.src[3] = feat4; ta.dst[3] = fT4; ta.C[3] = 1024; ta.HW[3] = 100;  ta.tx[3] = 4;
  ta.src[4] = W1;    ta.dst[4] = W1T; ta.C[4] = 1920; ta.HW[4] = 256;  ta.tx[4] = 8;
  ta.src[5] = W2;    ta.dst[5] = W2T; ta.C[5] = 256;  ta.HW[5] = 256;  ta.tx[5] = 8;
  int n_tiles = 0;
  for (int s = 0; s < 6; ++s) {
    int ty = (ta.C[s] + 31) / 32;
    int nbatch = (s < 4) ? NBATCH : 1;
    ta.tpb[s] = ta.tx[s] * ty;
    ta.start[s] = n_tiles;
    n_tiles += ta.tpb[s] * nbatch;
  }
  int mid_grid = 72 + (n_tiles + 3) / 4;
  mid_kernel<<<mid_grid, dim3(32, 32), 0, stream>>>(ta, conf, preds, cls, ghist, ctr,
                                                    cand_v, cand_i, boxes, keep, orighw, out,
                                                    n_tiles);

  roi_kernel<<<2400, 256, 0, stream>>>(boxes, fT1, fT2, fT3, fT4, fmat);
  gemm_tile_kernel<<<dim3(38, 4), 256, 0, stream>>>(fmat, W1T, b1, h1b, nullptr, nullptr,
                                                    2400, 256, 1920, 0, 0);
  gemm_tile_kernel<<<dim3(38, 4), 256, 0, stream>>>(h1b, W2T, b2, nullptr, out, keep,
                                                    2400, 256, 256, 260, 4);
}